// Round 5
// baseline (254.710 us; speedup 1.0000x reference)
//
#include <hip/hip_runtime.h>

#define B_ 4
#define L_ 4096
#define D_ 64
#define N_ 16
#define CHUNK 16
#define NCHUNK (L_ / CHUNK)        // 256
#define TOTCHUNK (B_ * NCHUNK)     // 1024

constexpr float DT_  = 0.1f;
constexpr float EPS_ = 1e-6f;

// ---------------------------------------------------------------------------
// K1: fused projection + DENSE-MATRIX chunk scan (round-4 proven) + NEW:
// last-block-per-batch cross-chunk combine folded into the tail (replaces the
// K2 dispatch entirely).
//
// Dense-matrix algebra (verified rounds 3/4):
//   a[s,n] = exp(An*delta_s)  =>  decay products are exp(An*(Ds[s]-Ds[j]))
//   with Ds = prefix-sum(delta):
//     out_local = M @ x_chunk,   M[s,j] = sum_n cm[s,n]*exp(An*(Ds-Dj))*g[j,n]
//     S_local   = Wnj @ x_chunk, Wnj[j,n] = exp(An*(Ds15-Dsj))*g[j,n]
//     Wcor[s,n] = cm[s,n]*exp(An*Ds[s]),  Cdec[n] = exp(An*Ds15)
//
// Combine tail (threadfence-reduction pattern, NO spin — deadlock-free):
//   every block: stores -> __threadfence() -> barrier -> tid0 atomicAdd ticket.
//   The last block per batch (ticket == NCHUNK-1) re-fences (acquire) and runs
//   the 256-chunk exclusive scan for all 16 n-chains: thread t owns
//   (n = t>>4, d0 = (t&15)*4), float4 state, G-deep prefetch (K2's proven
//   structure). 4 combiner blocks run concurrently (one per batch).
// ---------------------------------------------------------------------------
__global__ __launch_bounds__(256, 4) void proj_scan_kernel(
    const float* __restrict__ x,  const float* __restrict__ A,
    const float* __restrict__ Wb, const float* __restrict__ bb,
    const float* __restrict__ Wc, const float* __restrict__ bc,
    const float* __restrict__ Wd, const float* __restrict__ bd,
    float* __restrict__ S, float* __restrict__ Cdec,
    float* __restrict__ Wcor, float* __restrict__ out,
    int* __restrict__ cnt)
{
    const int gc    = blockIdx.x;              // global chunk 0..1023
    const int batch = gc >> 8;
    const int c     = gc & (NCHUNK - 1);
    const int tid   = threadIdx.x;
    const int w     = tid >> 6;                // wave 0..3
    const int lane  = tid & 63;
    const int base0 = batch * L_ + c * CHUNK;

    __shared__ float xs[CHUNK * D_];           // 4 KB
    __shared__ float AnS[N_];
    __shared__ float dl[CHUNK];                // per-step delta
    __shared__ float DsS[CHUNK];               // prefix sums of delta
    __shared__ float bmS[CHUNK * N_];          // 1 KB  Bm[s][n]
    __shared__ float cmS[CHUNK * N_];          // 1 KB  Cm[s][n]
    __shared__ float gT[N_ * CHUNK];           // 1 KB  g[n][j]  (transposed)
    __shared__ float uS[CHUNK * N_];           // 1 KB  Wcor[s][n]
    __shared__ float wnjS[CHUNK * N_];         // 1 KB  Wnj[j][n]
    __shared__ float MS[CHUNK * CHUNK];        // 1 KB  M[s][j]
    __shared__ int   lastFlag;

    // ---- stage x (256 float4, one per thread) + A row ----
    ((float4*)xs)[tid] = ((const float4*)(x + (size_t)base0 * D_))[tid];
    if (tid < N_) AnS[tid] = A[tid];           // rows of (D,N) identical

    // ---- W rows in registers (per-wave; overlaps staging latency) ----
    const int o  = lane & 31;                  // 0-15 -> Bm row, 16-31 -> Cm row
    const int h2 = lane >> 5;                  // K-half
    float wreg[32];
    const float* Wrow = (o < 16) ? (Wb + o * D_) : (Wc + (o - 16) * D_);
    const float4* w4p = (const float4*)(Wrow + h2 * 32);
    #pragma unroll
    for (int j = 0; j < 8; j++) {
        float4 w4 = w4p[j];
        wreg[4*j+0] = w4.x; wreg[4*j+1] = w4.y;
        wreg[4*j+2] = w4.z; wreg[4*j+3] = w4.w;
    }
    const float wd   = Wd[lane];
    const float bd0  = bd[0];
    const float bias = (o < 16) ? bb[o] : bc[o - 16];

    __syncthreads();

    // ---- deltas for this wave's 4 steps (s = 4w..4w+3) ----
    const int s0 = w * 4;
    float r[4];
    #pragma unroll
    for (int p = 0; p < 4; p++) r[p] = xs[(s0 + p) * D_ + lane] * wd;
    #pragma unroll
    for (int m = 32; m >= 1; m >>= 1) {
        #pragma unroll
        for (int p = 0; p < 4; p++) r[p] += __shfl_xor(r[p], m, 64);
    }
    #pragma unroll
    for (int p = 0; p < 4; p++) {
        float z = r[p] + bd0;
        float dlt = fmaxf(z, 0.0f) + log1pf(expf(-fabsf(z))) + DT_;
        if (lane == 0) dl[s0 + p] = dlt;
    }

    // ---- Bm/Cm dots for this wave's 4 steps -> LDS ----
    #pragma unroll
    for (int p = 0; p < 4; p++) {
        const int s = s0 + p;
        float acc = 0.0f;
        const float4* xs4 = (const float4*)(xs + s * D_ + h2 * 32);
        #pragma unroll
        for (int j = 0; j < 8; j++) {
            float4 v = xs4[j];                 // broadcast LDS reads
            acc += v.x * wreg[4*j+0] + v.y * wreg[4*j+1]
                 + v.z * wreg[4*j+2] + v.w * wreg[4*j+3];
        }
        acc += __shfl_xor(acc, 32, 64);        // lanes 0-31 hold full dots
        if (lane < 16)      bmS[s * 16 + lane]        = acc + bias;
        else if (lane < 32) cmS[s * 16 + (lane - 16)] = acc + bias;
    }
    __syncthreads();

    // ---- per-(s,n) phase: one thread per cell ----
    {
        const int s = tid >> 4, n = tid & 15;
        float ds = 0.0f, dsF = 0.0f;
        #pragma unroll
        for (int k = 0; k < CHUNK; k++) {
            float v = dl[k];
            dsF += v;
            if (k <= s) ds += v;
        }
        const float An  = AnS[n];
        const float dls = dl[s];
        const float tmp = An * dls;
        const float a   = expf(tmp);
        const float g   = (a - 1.0f) * dls * bmS[tid] / (tmp + EPS_);
        gT[n * 16 + s]  = g;                          // transposed for M build
        uS[tid]         = cmS[tid] * expf(An * ds);   // Wcor[s][n]
        wnjS[tid]       = expf(An * (dsF - ds)) * g;  // Wnj[j=s][n]
        if (n == 0) DsS[s] = ds;
        if (tid < 16) Cdec[gc * N_ + tid] = expf(AnS[tid] * dsF);
    }
    __syncthreads();

    // ---- M build: thread (s,j) does a 16-term n-sum (16 exps, all <=0) ----
    {
        const int s = tid >> 4, j = tid & 15;
        float m = 0.0f;
        if (j <= s) {
            const float dd = DsS[s] - DsS[j];         // >= 0
            #pragma unroll
            for (int n = 0; n < N_; n++)
                m += cmS[s * 16 + n] * expf(AnS[n] * dd) * gT[n * 16 + j];
        }
        MS[tid] = m;
    }
    __syncthreads();

    // ---- two 16x16 @ 16x64 GEMMs: out_local and S_local ----
    const int d = lane;
    #pragma unroll
    for (int k = 0; k < 4; k++) {
        const int sn = w * 4 + k;                     // doubles as s and n
        float acc = 0.0f, acc2 = 0.0f;
        #pragma unroll
        for (int j = 0; j < CHUNK; j++) {
            const float xv = xs[j * 64 + d];
            acc  += MS[sn * 16 + j]   * xv;           // M row: wave-uniform bcast
            acc2 += wnjS[j * 16 + sn] * xv;           // Wnj col: bcast
        }
        out[(size_t)(base0 + sn) * D_ + d] = acc;     // local (zero-init) output
        S[(size_t)(gc * N_ + sn) * D_ + d] = acc2;    // chunk-final local state
    }

    // ---- coalesced blast of Wcor (256 floats = 64 float4) ----
    if (tid < 64)
        ((float4*)(Wcor + (size_t)base0 * 16))[tid] = ((const float4*)uS)[tid];

    // ======================================================================
    // Combine tail: threadfence-reduction, last block per batch does the
    // cross-chunk exclusive scan (replaces the K2 dispatch).
    // ======================================================================
    __threadfence();                        // make this thread's stores visible
    __syncthreads();                        // all threads fenced before ticket
    if (tid == 0)
        lastFlag = (atomicAdd(&cnt[batch], 1) == NCHUNK - 1);
    __syncthreads();
    if (!lastFlag) return;                  // 1020 blocks exit immediately
    __threadfence();                        // acquire: invalidate stale caches

    // combiner: thread t owns (n = t>>4, d0 = (t&15)*4), float4 run state
    const int n  = tid >> 4;
    const int d0 = (tid & 15) * 4;
    const int cb = batch * NCHUNK;
    float*       pS = S    + (size_t)(cb * N_ + n) * D_ + d0;  // +N_*D_ per chunk
    const float* pA = Cdec + cb * N_ + n;                      // +N_ per chunk

#define GPF 8
    float4 run = make_float4(0.f, 0.f, 0.f, 0.f);
    float4 tv[GPF]; float ta[GPF];
    #pragma unroll
    for (int j = 0; j < GPF; j++) {
        tv[j] = *(const float4*)(pS + (size_t)j * (N_ * D_));
        ta[j] = pA[j * N_];
    }
    for (int cc = 0; cc < NCHUNK; cc += GPF) {
        const int cn = (cc + GPF < NCHUNK) ? (cc + GPF) : cc;  // last: dummy
        float4 nv[GPF]; float na[GPF];
        #pragma unroll
        for (int j = 0; j < GPF; j++) {
            nv[j] = *(const float4*)(pS + (size_t)(cn + j) * (N_ * D_));
            na[j] = pA[(cn + j) * N_];
        }
        #pragma unroll
        for (int j = 0; j < GPF; j++) {
            *(float4*)(pS + (size_t)(cc + j) * (N_ * D_)) = run;  // exclusive
            run.x = ta[j] * run.x + tv[j].x;
            run.y = ta[j] * run.y + tv[j].y;
            run.z = ta[j] * run.z + tv[j].z;
            run.w = ta[j] * run.w + tv[j].w;
        }
        #pragma unroll
        for (int j = 0; j < GPF; j++) { tv[j] = nv[j]; ta[j] = na[j]; }
    }
}

// ---------------------------------------------------------------------------
// K3: apply correction: out[l,d] += sum_n Wcor_l[n] * hi[n,d].
// 1024 blocks x 256 threads. hi staged once through LDS; all global loads
// issued before the sync so their latencies overlap. (Round-4 proven.)
// ---------------------------------------------------------------------------
__global__ __launch_bounds__(256) void apply_kernel(
    const float* __restrict__ Wcor, const float* __restrict__ S,
    float* __restrict__ out)
{
    const int gc    = blockIdx.x;
    const int batch = gc >> 8;
    const int c     = gc & (NCHUNK - 1);
    const int tid   = threadIdx.x;
    const int w     = tid >> 6;
    const int lane  = tid & 63;
    const int base0 = batch * L_ + c * CHUNK;

    __shared__ float wl[CHUNK * N_];           // 1 KB
    __shared__ float his[N_ * D_];             // 4 KB

    // stage chunk-initial state (post-combine S): 256 float4, one per thread
    ((float4*)his)[tid] = ((const float4*)(S + (size_t)gc * N_ * D_))[tid];

    // stage correction matrix (256 floats = 64 float4)
    if (tid < 64)
        ((float4*)wl)[tid] = ((const float4*)(Wcor + (size_t)base0 * 16))[tid];

    // prefetch this wave's 4 out rows
    const int s0 = w * 4;
    float oreg[4];
    #pragma unroll
    for (int p = 0; p < 4; p++)
        oreg[p] = out[(size_t)(base0 + s0 + p) * D_ + lane];

    __syncthreads();

    #pragma unroll
    for (int p = 0; p < 4; p++) {
        const int s = s0 + p;
        float a = oreg[p];
        #pragma unroll
        for (int n = 0; n < N_; n++)
            a += wl[s * 16 + n] * his[n * 64 + lane];   // bcast * conflict-free
        out[(size_t)(base0 + s) * D_ + lane] = a;
    }
}

// ---------------------------------------------------------------------------
extern "C" void kernel_launch(void* const* d_in, const int* in_sizes, int n_in,
                              void* d_out, int out_size, void* d_ws, size_t ws_size,
                              hipStream_t stream)
{
    const float* x  = (const float*)d_in[0];
    const float* A  = (const float*)d_in[1];
    const float* Wb = (const float*)d_in[2];
    const float* bb = (const float*)d_in[3];
    const float* Wc = (const float*)d_in[4];
    const float* bc = (const float*)d_in[5];
    const float* Wd = (const float*)d_in[6];
    const float* bd = (const float*)d_in[7];
    float* out = (float*)d_out;

    // ws carve (floats): S 4MB | Cdec 64KB | Wcor 1MB | cnt 16B
    float* S    = (float*)d_ws;
    float* Cdec = S    + (size_t)TOTCHUNK * N_ * D_;
    float* Wcor = Cdec + (size_t)TOTCHUNK * N_;
    int*   cnt  = (int*)(Wcor + (size_t)TOTCHUNK * CHUNK * N_);

    // zero the per-batch tickets (workspace is poisoned before every launch);
    // async memset is graph-capture-safe (becomes a memset node)
    hipMemsetAsync(cnt, 0, B_ * sizeof(int), stream);

    proj_scan_kernel<<<TOTCHUNK, 256, 0, stream>>>(x, A, Wb, bb, Wc, bc, Wd, bd,
                                                   S, Cdec, Wcor, out, cnt);
    apply_kernel<<<TOTCHUNK, 256, 0, stream>>>(Wcor, S, out);
}

// Round 6
// 152.487 us; speedup vs baseline: 1.6704x; 1.6704x over previous
//
#include <hip/hip_runtime.h>

#define B_ 4
#define L_ 4096
#define D_ 64
#define N_ 16
#define CHUNK 16
#define NCHUNK (L_ / CHUNK)        // 256
#define TOTCHUNK (B_ * NCHUNK)     // 1024

constexpr float DT_  = 0.1f;
constexpr float EPS_ = 1e-6f;

// ---------------------------------------------------------------------------
// K1: fused projection + DENSE-MATRIX chunk scan. VERBATIM round-4 kernel
// (passed twice at 100.3/100.7 µs total). No fences, no atomics.
//   a[s,n] = exp(An*delta_s)  =>  decay products are exp(An*(Ds[s]-Ds[j]))
//   with Ds = prefix-sum(delta):
//     out_local = M @ x_chunk,   M[s,j] = sum_n cm[s,n]*exp(An*(Ds-Dj))*g[j,n]
//     S_local   = Wnj @ x_chunk, Wnj[j,n] = exp(An*(Ds15-Dsj))*g[j,n]
//     Wcor[s,n] = cm[s,n]*exp(An*Ds[s]),  Cdec[n] = exp(An*Ds15)
// S now stays chunk-LOCAL (combine no longer overwrites it).
// ---------------------------------------------------------------------------
__global__ __launch_bounds__(256) void proj_scan_kernel(
    const float* __restrict__ x,  const float* __restrict__ A,
    const float* __restrict__ Wb, const float* __restrict__ bb,
    const float* __restrict__ Wc, const float* __restrict__ bc,
    const float* __restrict__ Wd, const float* __restrict__ bd,
    float* __restrict__ S, float* __restrict__ Cdec,
    float* __restrict__ Wcor, float* __restrict__ out)
{
    const int gc    = blockIdx.x;              // global chunk 0..1023
    const int batch = gc >> 8;
    const int c     = gc & (NCHUNK - 1);
    const int tid   = threadIdx.x;
    const int w     = tid >> 6;                // wave 0..3
    const int lane  = tid & 63;
    const int base0 = batch * L_ + c * CHUNK;

    __shared__ float xs[CHUNK * D_];           // 4 KB
    __shared__ float AnS[N_];
    __shared__ float dl[CHUNK];                // per-step delta
    __shared__ float DsS[CHUNK];               // prefix sums of delta
    __shared__ float bmS[CHUNK * N_];          // 1 KB  Bm[s][n]
    __shared__ float cmS[CHUNK * N_];          // 1 KB  Cm[s][n]
    __shared__ float gT[N_ * CHUNK];           // 1 KB  g[n][j]  (transposed)
    __shared__ float uS[CHUNK * N_];           // 1 KB  Wcor[s][n]
    __shared__ float wnjS[CHUNK * N_];         // 1 KB  Wnj[j][n]
    __shared__ float MS[CHUNK * CHUNK];        // 1 KB  M[s][j]

    // ---- stage x (256 float4, one per thread) + A row ----
    ((float4*)xs)[tid] = ((const float4*)(x + (size_t)base0 * D_))[tid];
    if (tid < N_) AnS[tid] = A[tid];           // rows of (D,N) identical

    // ---- W rows in registers (per-wave; overlaps staging latency) ----
    const int o  = lane & 31;                  // 0-15 -> Bm row, 16-31 -> Cm row
    const int h2 = lane >> 5;                  // K-half
    float wreg[32];
    const float* Wrow = (o < 16) ? (Wb + o * D_) : (Wc + (o - 16) * D_);
    const float4* w4p = (const float4*)(Wrow + h2 * 32);
    #pragma unroll
    for (int j = 0; j < 8; j++) {
        float4 w4 = w4p[j];
        wreg[4*j+0] = w4.x; wreg[4*j+1] = w4.y;
        wreg[4*j+2] = w4.z; wreg[4*j+3] = w4.w;
    }
    const float wd   = Wd[lane];
    const float bd0  = bd[0];
    const float bias = (o < 16) ? bb[o] : bc[o - 16];

    __syncthreads();

    // ---- deltas for this wave's 4 steps (s = 4w..4w+3) ----
    const int s0 = w * 4;
    float r[4];
    #pragma unroll
    for (int p = 0; p < 4; p++) r[p] = xs[(s0 + p) * D_ + lane] * wd;
    #pragma unroll
    for (int m = 32; m >= 1; m >>= 1) {
        #pragma unroll
        for (int p = 0; p < 4; p++) r[p] += __shfl_xor(r[p], m, 64);
    }
    #pragma unroll
    for (int p = 0; p < 4; p++) {
        float z = r[p] + bd0;
        float dlt = fmaxf(z, 0.0f) + log1pf(expf(-fabsf(z))) + DT_;
        if (lane == 0) dl[s0 + p] = dlt;
    }

    // ---- Bm/Cm dots for this wave's 4 steps -> LDS ----
    #pragma unroll
    for (int p = 0; p < 4; p++) {
        const int s = s0 + p;
        float acc = 0.0f;
        const float4* xs4 = (const float4*)(xs + s * D_ + h2 * 32);
        #pragma unroll
        for (int j = 0; j < 8; j++) {
            float4 v = xs4[j];                 // broadcast LDS reads
            acc += v.x * wreg[4*j+0] + v.y * wreg[4*j+1]
                 + v.z * wreg[4*j+2] + v.w * wreg[4*j+3];
        }
        acc += __shfl_xor(acc, 32, 64);        // lanes 0-31 hold full dots
        if (lane < 16)      bmS[s * 16 + lane]        = acc + bias;
        else if (lane < 32) cmS[s * 16 + (lane - 16)] = acc + bias;
    }
    __syncthreads();

    // ---- per-(s,n) phase: one thread per cell ----
    {
        const int s = tid >> 4, n = tid & 15;
        float ds = 0.0f, dsF = 0.0f;
        #pragma unroll
        for (int k = 0; k < CHUNK; k++) {
            float v = dl[k];
            dsF += v;
            if (k <= s) ds += v;
        }
        const float An  = AnS[n];
        const float dls = dl[s];
        const float tmp = An * dls;
        const float a   = expf(tmp);
        const float g   = (a - 1.0f) * dls * bmS[tid] / (tmp + EPS_);
        gT[n * 16 + s]  = g;                          // transposed for M build
        uS[tid]         = cmS[tid] * expf(An * ds);   // Wcor[s][n]
        wnjS[tid]       = expf(An * (dsF - ds)) * g;  // Wnj[j=s][n]
        if (n == 0) DsS[s] = ds;
        if (tid < 16) Cdec[gc * N_ + tid] = expf(AnS[tid] * dsF);
    }
    __syncthreads();

    // ---- M build: thread (s,j) does a 16-term n-sum (16 exps, all <=0) ----
    {
        const int s = tid >> 4, j = tid & 15;
        float m = 0.0f;
        if (j <= s) {
            const float dd = DsS[s] - DsS[j];         // >= 0
            #pragma unroll
            for (int n = 0; n < N_; n++)
                m += cmS[s * 16 + n] * expf(AnS[n] * dd) * gT[n * 16 + j];
        }
        MS[tid] = m;
    }
    __syncthreads();

    // ---- two 16x16 @ 16x64 GEMMs: out_local and S_local ----
    const int d = lane;
    #pragma unroll
    for (int k = 0; k < 4; k++) {
        const int sn = w * 4 + k;                     // doubles as s and n
        float acc = 0.0f, acc2 = 0.0f;
        #pragma unroll
        for (int j = 0; j < CHUNK; j++) {
            const float xv = xs[j * 64 + d];
            acc  += MS[sn * 16 + j]   * xv;           // M row: wave-uniform bcast
            acc2 += wnjS[j * 16 + sn] * xv;           // Wnj col: bcast
        }
        out[(size_t)(base0 + sn) * D_ + d] = acc;     // local (zero-init) output
        S[(size_t)(gc * N_ + sn) * D_ + d] = acc2;    // chunk-final LOCAL state
    }

    // ---- coalesced blast of Wcor (256 floats = 64 float4) ----
    if (tid < 64)
        ((float4*)(Wcor + (size_t)base0 * 16))[tid] = ((const float4*)uS)[tid];
}

// ---------------------------------------------------------------------------
// K23: combine + apply fused via REDUNDANT prefix recomputation (fence-free).
// 64 blocks x 256 threads; block = (batch, slice): owns 16 consecutive chunks
// [c0, c0+16). Phase 1: walk chunks 0..c0-1 folding (S_local, Cdec) into a
// distributed running state P (thread t owns n=t>>4, d-quad t&15) with the
// proven G=8 float4-prefetch pipeline (max 240 serial steps, blocks run
// concurrently so wall = worst block ~8µs). Phase 2: per owned chunk, publish
// P -> LDS his, stage Wcor -> LDS wl, apply out += Wcor @ hi, fold chunk.
// 1-deep prefetch of next chunk's loads hides global latency under the apply.
// No atomics, no fences: the only cross-block dependency is through the
// dispatch barrier after K1.
// ---------------------------------------------------------------------------
#define GPF 8
__global__ __launch_bounds__(256) void combine_apply(
    const float* __restrict__ Wcor, const float* __restrict__ S,
    const float* __restrict__ Cdec, float* __restrict__ out)
{
    const int blk   = blockIdx.x;              // 0..63
    const int batch = blk >> 4;                // 16 slices per batch
    const int slice = blk & 15;
    const int tid   = threadIdx.x;
    const int w     = tid >> 6;                // wave 0..3
    const int lane  = tid & 63;
    const int cb    = batch * NCHUNK;
    const int c0    = slice * (NCHUNK / 16);   // first owned chunk

    __shared__ float his[N_ * D_];             // 4 KB
    __shared__ float wl[CHUNK * N_];           // 1 KB

    // distributed P: thread t owns (n = t>>4, d0 = (t&15)*4)
    const int n  = tid >> 4;
    const int d0 = (tid & 15) * 4;
    const float* pS = S    + (size_t)(cb * N_ + n) * D_ + d0;  // +N_*D_/chunk
    const float* pA = Cdec + cb * N_ + n;                      // +N_/chunk

    float4 P = make_float4(0.f, 0.f, 0.f, 0.f);

    // ---- phase 1: fold chunks 0..c0-1 (c0 is a multiple of GPF) ----
    if (c0 > 0) {
        float4 tv[GPF]; float ta[GPF];
        #pragma unroll
        for (int j = 0; j < GPF; j++) {
            tv[j] = *(const float4*)(pS + (size_t)j * (N_ * D_));
            ta[j] = pA[j * N_];
        }
        for (int cc = 0; cc < c0; cc += GPF) {
            const int cn = (cc + GPF < c0) ? (cc + GPF) : cc;  // last: dummy
            float4 nv[GPF]; float na[GPF];
            #pragma unroll
            for (int j = 0; j < GPF; j++) {
                nv[j] = *(const float4*)(pS + (size_t)(cn + j) * (N_ * D_));
                na[j] = pA[(cn + j) * N_];
            }
            #pragma unroll
            for (int j = 0; j < GPF; j++) {
                P.x = ta[j] * P.x + tv[j].x;
                P.y = ta[j] * P.y + tv[j].y;
                P.z = ta[j] * P.z + tv[j].z;
                P.w = ta[j] * P.w + tv[j].w;
            }
            #pragma unroll
            for (int j = 0; j < GPF; j++) { tv[j] = nv[j]; ta[j] = na[j]; }
        }
    }

    // ---- phase 2: apply + fold for the 16 owned chunks (1-deep prefetch) ----
    int cc    = c0;
    int base0 = batch * L_ + cc * CHUNK;
    float4 svA = *(const float4*)(pS + (size_t)cc * (N_ * D_));
    float  avA = pA[cc * N_];
    float4 wcA = make_float4(0.f, 0.f, 0.f, 0.f);
    float  oregA[4];
    if (tid < 64) wcA = ((const float4*)(Wcor + (size_t)base0 * 16))[tid];
    #pragma unroll
    for (int p = 0; p < 4; p++)
        oregA[p] = out[(size_t)(base0 + w * 4 + p) * D_ + lane];

    for (int k = 0; k < NCHUNK / 16; k++) {
        cc    = c0 + k;
        base0 = batch * L_ + cc * CHUNK;

        __syncthreads();                       // prior apply done with his/wl
        ((float4*)his)[tid] = P;               // his[n][d] float4 idx == tid
        if (tid < 64) ((float4*)wl)[tid] = wcA;

        // prefetch next chunk's loads (fly under the sync + apply below)
        float4 svB = svA; float avB = avA; float4 wcB = wcA;
        float  oregB[4];
        if (k + 1 < NCHUNK / 16) {
            const int c2 = cc + 1;
            const int b2 = batch * L_ + c2 * CHUNK;
            svB = *(const float4*)(pS + (size_t)c2 * (N_ * D_));
            avB = pA[c2 * N_];
            if (tid < 64) wcB = ((const float4*)(Wcor + (size_t)b2 * 16))[tid];
            #pragma unroll
            for (int p = 0; p < 4; p++)
                oregB[p] = out[(size_t)(b2 + w * 4 + p) * D_ + lane];
        } else {
            #pragma unroll
            for (int p = 0; p < 4; p++) oregB[p] = 0.f;
        }
        __syncthreads();                       // his/wl published

        #pragma unroll
        for (int p = 0; p < 4; p++) {
            const int s = w * 4 + p;
            float a = oregA[p];
            #pragma unroll
            for (int nn = 0; nn < N_; nn++)
                a += wl[s * 16 + nn] * his[nn * 64 + lane];  // bcast*no-conflict
            out[(size_t)(base0 + s) * D_ + lane] = a;
        }

        // fold chunk cc into P
        P.x = avA * P.x + svA.x;
        P.y = avA * P.y + svA.y;
        P.z = avA * P.z + svA.z;
        P.w = avA * P.w + svA.w;

        svA = svB; avA = avB; wcA = wcB;
        #pragma unroll
        for (int p = 0; p < 4; p++) oregA[p] = oregB[p];
    }
}

// ---------------------------------------------------------------------------
extern "C" void kernel_launch(void* const* d_in, const int* in_sizes, int n_in,
                              void* d_out, int out_size, void* d_ws, size_t ws_size,
                              hipStream_t stream)
{
    const float* x  = (const float*)d_in[0];
    const float* A  = (const float*)d_in[1];
    const float* Wb = (const float*)d_in[2];
    const float* bb = (const float*)d_in[3];
    const float* Wc = (const float*)d_in[4];
    const float* bc = (const float*)d_in[5];
    const float* Wd = (const float*)d_in[6];
    const float* bd = (const float*)d_in[7];
    float* out = (float*)d_out;

    // ws carve (floats): S 4MB | Cdec 64KB | Wcor 1MB
    float* S    = (float*)d_ws;
    float* Cdec = S    + (size_t)TOTCHUNK * N_ * D_;
    float* Wcor = Cdec + (size_t)TOTCHUNK * N_;

    proj_scan_kernel<<<TOTCHUNK, 256, 0, stream>>>(x, A, Wb, bb, Wc, bc, Wd, bd,
                                                   S, Cdec, Wcor, out);
    combine_apply<<<B_ * N_, 256, 0, stream>>>(Wcor, S, Cdec, out);
}

// Round 7
// 100.220 us; speedup vs baseline: 2.5415x; 1.5215x over previous
//
#include <hip/hip_runtime.h>

#define B_ 4
#define L_ 4096
#define D_ 64
#define N_ 16
#define CHUNK 16
#define NCHUNK (L_ / CHUNK)        // 256
#define TOTCHUNK (B_ * NCHUNK)     // 1024

constexpr float DT_  = 0.1f;
constexpr float EPS_ = 1e-6f;

// ---------------------------------------------------------------------------
// K1: fused projection + DENSE-MATRIX chunk scan (round-4 proven, 100.7 µs
// total; round-2 scan variant 100.3 — tied). One change vs round 4: the Wcor
// global blast is issued right after uS is final (post (s,n)-phase sync), so
// its ~1KB/block global write flies under M-build + the two GEMMs instead of
// serializing on the block tail.
//   a[s,n] = exp(An*delta_s)  =>  decay products are exp(An*(Ds[s]-Ds[j]))
//   with Ds = prefix-sum(delta):
//     out_local = M @ x_chunk,   M[s,j] = sum_n cm[s,n]*exp(An*(Ds-Dj))*g[j,n]
//     S_local   = Wnj @ x_chunk, Wnj[j,n] = exp(An*(Ds15-Dsj))*g[j,n]
//     Wcor[s,n] = cm[s,n]*exp(An*Ds[s]),  Cdec[n] = exp(An*Ds15)
// ---------------------------------------------------------------------------
__global__ __launch_bounds__(256) void proj_scan_kernel(
    const float* __restrict__ x,  const float* __restrict__ A,
    const float* __restrict__ Wb, const float* __restrict__ bb,
    const float* __restrict__ Wc, const float* __restrict__ bc,
    const float* __restrict__ Wd, const float* __restrict__ bd,
    float* __restrict__ S, float* __restrict__ Cdec,
    float* __restrict__ Wcor, float* __restrict__ out)
{
    const int gc    = blockIdx.x;              // global chunk 0..1023
    const int batch = gc >> 8;
    const int c     = gc & (NCHUNK - 1);
    const int tid   = threadIdx.x;
    const int w     = tid >> 6;                // wave 0..3
    const int lane  = tid & 63;
    const int base0 = batch * L_ + c * CHUNK;

    __shared__ float xs[CHUNK * D_];           // 4 KB
    __shared__ float AnS[N_];
    __shared__ float dl[CHUNK];                // per-step delta
    __shared__ float DsS[CHUNK];               // prefix sums of delta
    __shared__ float bmS[CHUNK * N_];          // 1 KB  Bm[s][n]
    __shared__ float cmS[CHUNK * N_];          // 1 KB  Cm[s][n]
    __shared__ float gT[N_ * CHUNK];           // 1 KB  g[n][j]  (transposed)
    __shared__ float uS[CHUNK * N_];           // 1 KB  Wcor[s][n]
    __shared__ float wnjS[CHUNK * N_];         // 1 KB  Wnj[j][n]
    __shared__ float MS[CHUNK * CHUNK];        // 1 KB  M[s][j]

    // ---- stage x (256 float4, one per thread) + A row ----
    ((float4*)xs)[tid] = ((const float4*)(x + (size_t)base0 * D_))[tid];
    if (tid < N_) AnS[tid] = A[tid];           // rows of (D,N) identical

    // ---- W rows in registers (per-wave; overlaps staging latency) ----
    const int o  = lane & 31;                  // 0-15 -> Bm row, 16-31 -> Cm row
    const int h2 = lane >> 5;                  // K-half
    float wreg[32];
    const float* Wrow = (o < 16) ? (Wb + o * D_) : (Wc + (o - 16) * D_);
    const float4* w4p = (const float4*)(Wrow + h2 * 32);
    #pragma unroll
    for (int j = 0; j < 8; j++) {
        float4 w4 = w4p[j];
        wreg[4*j+0] = w4.x; wreg[4*j+1] = w4.y;
        wreg[4*j+2] = w4.z; wreg[4*j+3] = w4.w;
    }
    const float wd   = Wd[lane];
    const float bd0  = bd[0];
    const float bias = (o < 16) ? bb[o] : bc[o - 16];

    __syncthreads();

    // ---- deltas for this wave's 4 steps (s = 4w..4w+3) ----
    const int s0 = w * 4;
    float r[4];
    #pragma unroll
    for (int p = 0; p < 4; p++) r[p] = xs[(s0 + p) * D_ + lane] * wd;
    #pragma unroll
    for (int m = 32; m >= 1; m >>= 1) {
        #pragma unroll
        for (int p = 0; p < 4; p++) r[p] += __shfl_xor(r[p], m, 64);
    }
    #pragma unroll
    for (int p = 0; p < 4; p++) {
        float z = r[p] + bd0;
        float dlt = fmaxf(z, 0.0f) + log1pf(expf(-fabsf(z))) + DT_;
        if (lane == 0) dl[s0 + p] = dlt;
    }

    // ---- Bm/Cm dots for this wave's 4 steps -> LDS ----
    #pragma unroll
    for (int p = 0; p < 4; p++) {
        const int s = s0 + p;
        float acc = 0.0f;
        const float4* xs4 = (const float4*)(xs + s * D_ + h2 * 32);
        #pragma unroll
        for (int j = 0; j < 8; j++) {
            float4 v = xs4[j];                 // broadcast LDS reads
            acc += v.x * wreg[4*j+0] + v.y * wreg[4*j+1]
                 + v.z * wreg[4*j+2] + v.w * wreg[4*j+3];
        }
        acc += __shfl_xor(acc, 32, 64);        // lanes 0-31 hold full dots
        if (lane < 16)      bmS[s * 16 + lane]        = acc + bias;
        else if (lane < 32) cmS[s * 16 + (lane - 16)] = acc + bias;
    }
    __syncthreads();

    // ---- per-(s,n) phase: one thread per cell ----
    {
        const int s = tid >> 4, n = tid & 15;
        float ds = 0.0f, dsF = 0.0f;
        #pragma unroll
        for (int k = 0; k < CHUNK; k++) {
            float v = dl[k];
            dsF += v;
            if (k <= s) ds += v;
        }
        const float An  = AnS[n];
        const float dls = dl[s];
        const float tmp = An * dls;
        const float a   = expf(tmp);
        const float g   = (a - 1.0f) * dls * bmS[tid] / (tmp + EPS_);
        gT[n * 16 + s]  = g;                          // transposed for M build
        uS[tid]         = cmS[tid] * expf(An * ds);   // Wcor[s][n]
        wnjS[tid]       = expf(An * (dsF - ds)) * g;  // Wnj[j=s][n]
        if (n == 0) DsS[s] = ds;
        if (tid < 16) Cdec[gc * N_ + tid] = expf(AnS[tid] * dsF);
    }
    __syncthreads();

    // ---- Wcor blast EARLY: uS is final; store flies under M-build+GEMMs ----
    if (tid < 64)
        ((float4*)(Wcor + (size_t)base0 * 16))[tid] = ((const float4*)uS)[tid];

    // ---- M build: thread (s,j) does a 16-term n-sum (16 exps, all <=0) ----
    {
        const int s = tid >> 4, j = tid & 15;
        float m = 0.0f;
        if (j <= s) {
            const float dd = DsS[s] - DsS[j];         // >= 0
            #pragma unroll
            for (int n = 0; n < N_; n++)
                m += cmS[s * 16 + n] * expf(AnS[n] * dd) * gT[n * 16 + j];
        }
        MS[tid] = m;
    }
    __syncthreads();

    // ---- two 16x16 @ 16x64 GEMMs: out_local and S_local ----
    const int d = lane;
    #pragma unroll
    for (int k = 0; k < 4; k++) {
        const int sn = w * 4 + k;                     // doubles as s and n
        float acc = 0.0f, acc2 = 0.0f;
        #pragma unroll
        for (int j = 0; j < CHUNK; j++) {
            const float xv = xs[j * 64 + d];
            acc  += MS[sn * 16 + j]   * xv;           // M row: wave-uniform bcast
            acc2 += wnjS[j * 16 + sn] * xv;           // Wnj col: bcast
        }
        out[(size_t)(base0 + sn) * D_ + d] = acc;     // local (zero-init) output
        S[(size_t)(gc * N_ + sn) * D_ + d] = acc2;    // chunk-final LOCAL state
    }
}

// ---------------------------------------------------------------------------
// K2: cross-chunk exclusive scan, 64 blocks x 64 threads; block = (b,n),
// thread = d. Groups of 32 with next-group prefetch: 64 loads in flight while
// a group's serial chain runs. (Round-0/2/4 proven config, verbatim.)
// ---------------------------------------------------------------------------
#define G_ 32
__global__ __launch_bounds__(64) void combine(
    float* __restrict__ S, const float* __restrict__ Cdec)
{
    const int b = blockIdx.x >> 4;
    const int n = blockIdx.x & 15;
    const int d = threadIdx.x;
    const int cb = b * NCHUNK;

    float*       baseS = S    + (size_t)(cb * N_ + n) * D_ + d;  // stride N_*D_ per chunk
    const float* baseA = Cdec + cb * N_ + n;                     // stride N_ per chunk

    float run = 0.0f;
    float sbuf[G_], abuf[G_];
    #pragma unroll
    for (int j = 0; j < G_; j++) {
        sbuf[j] = baseS[(size_t)j * (N_ * D_)];
        abuf[j] = baseA[j * N_];
    }
    for (int cc = 0; cc < NCHUNK; cc += G_) {
        const int cn = (cc + G_ < NCHUNK) ? (cc + G_) : cc;   // last: dummy reload
        float t[G_], u[G_];
        #pragma unroll
        for (int j = 0; j < G_; j++) {
            t[j] = baseS[(size_t)(cn + j) * (N_ * D_)];
            u[j] = baseA[(cn + j) * N_];
        }
        #pragma unroll
        for (int j = 0; j < G_; j++) {
            baseS[(size_t)(cc + j) * (N_ * D_)] = run;        // exclusive prefix
            run = abuf[j] * run + sbuf[j];
        }
        #pragma unroll
        for (int j = 0; j < G_; j++) { sbuf[j] = t[j]; abuf[j] = u[j]; }
    }
}

// ---------------------------------------------------------------------------
// K3: apply correction: out[l,d] += sum_n Wcor_l[n] * hi[n,d].
// 1024 blocks x 256 threads. hi staged once through LDS; all global loads
// issued before the sync so their latencies overlap. (Round-4 proven.)
// ---------------------------------------------------------------------------
__global__ __launch_bounds__(256) void apply_kernel(
    const float* __restrict__ Wcor, const float* __restrict__ S,
    float* __restrict__ out)
{
    const int gc    = blockIdx.x;
    const int batch = gc >> 8;
    const int c     = gc & (NCHUNK - 1);
    const int tid   = threadIdx.x;
    const int w     = tid >> 6;
    const int lane  = tid & 63;
    const int base0 = batch * L_ + c * CHUNK;

    __shared__ float wl[CHUNK * N_];           // 1 KB
    __shared__ float his[N_ * D_];             // 4 KB

    // stage chunk-initial state (post-combine S): 256 float4, one per thread
    ((float4*)his)[tid] = ((const float4*)(S + (size_t)gc * N_ * D_))[tid];

    // stage correction matrix (256 floats = 64 float4)
    if (tid < 64)
        ((float4*)wl)[tid] = ((const float4*)(Wcor + (size_t)base0 * 16))[tid];

    // prefetch this wave's 4 out rows
    const int s0 = w * 4;
    float oreg[4];
    #pragma unroll
    for (int p = 0; p < 4; p++)
        oreg[p] = out[(size_t)(base0 + s0 + p) * D_ + lane];

    __syncthreads();

    #pragma unroll
    for (int p = 0; p < 4; p++) {
        const int s = s0 + p;
        float a = oreg[p];
        #pragma unroll
        for (int n = 0; n < N_; n++)
            a += wl[s * 16 + n] * his[n * 64 + lane];   // bcast * conflict-free
        out[(size_t)(base0 + s) * D_ + lane] = a;
    }
}

// ---------------------------------------------------------------------------
extern "C" void kernel_launch(void* const* d_in, const int* in_sizes, int n_in,
                              void* d_out, int out_size, void* d_ws, size_t ws_size,
                              hipStream_t stream)
{
    const float* x  = (const float*)d_in[0];
    const float* A  = (const float*)d_in[1];
    const float* Wb = (const float*)d_in[2];
    const float* bb = (const float*)d_in[3];
    const float* Wc = (const float*)d_in[4];
    const float* bc = (const float*)d_in[5];
    const float* Wd = (const float*)d_in[6];
    const float* bd = (const float*)d_in[7];
    float* out = (float*)d_out;

    // ws carve (floats): S 4MB | Cdec 64KB | Wcor 1MB
    float* S    = (float*)d_ws;
    float* Cdec = S    + (size_t)TOTCHUNK * N_ * D_;
    float* Wcor = Cdec + (size_t)TOTCHUNK * N_;

    proj_scan_kernel<<<TOTCHUNK, 256, 0, stream>>>(x, A, Wb, bb, Wc, bc, Wd, bd,
                                                   S, Cdec, Wcor, out);
    combine<<<B_ * N_, 64, 0, stream>>>(S, Cdec);
    apply_kernel<<<TOTCHUNK, 256, 0, stream>>>(Wcor, S, out);
}